// Round 11
// baseline (4116.073 us; speedup 1.0000x reference)
//
#include <hip/hip_runtime.h>

#define NNODES 50000
#define NEDGES 1600000
#define INF 128
#define UNITS 64
#define OUTF 40
#define NLAYERS 6
#define NB2 782            // buckets = ceil(50000/64), bucket = dst >> 6
#define BCAP2 2560         // per-bucket capacity (mean 2046, +11 sigma)
#define CHUNK 8192         // edges per k_bin block
#define NBINB ((NEDGES + CHUNK - 1) / CHUNK)  // 196

#define WJK_OFS 114688     // byte offset of JK (w_last) blocks inside wbf
#define WBF_BYTES (114688 + 6 * 6144)
#define ZSENT NNODES       // sentinel all-zero z row
#define ZROWS (NNODES + 1)

typedef __attribute__((ext_vector_type(8))) short short8;
typedef __attribute__((ext_vector_type(4))) float f32x4;

__device__ __forceinline__ ushort f2bf(float f) {
  unsigned u = __float_as_uint(f);
  unsigned r = (u + 0x7fffu + ((u >> 16) & 1u)) >> 16;
  return (ushort)r;
}
__device__ __forceinline__ unsigned pack2(float a, float b) {
  return ((unsigned)f2bf(b) << 16) | (unsigned)f2bf(a);
}
__device__ __forceinline__ float2 bf2_unpack(unsigned v) {
  float2 r;
  r.x = __uint_as_float(v << 16);
  r.y = __uint_as_float(v & 0xffff0000u);
  return r;
}

// ---------------- edge binning: bucket = dst>>6, payload = (b<<22)|(src<<6)|(dst&63) ----
__global__ void k_bin(const int* __restrict__ src, const int* __restrict__ dst,
                      int* __restrict__ bucket_cursor, unsigned* __restrict__ binned) {
  __shared__ unsigned sh_pack[CHUNK];
  __shared__ int sh_cnt[NB2];
  __shared__ int sh_base[NB2];
  int tid = threadIdx.x;
  int e0 = blockIdx.x * CHUNK;
  int n = min(CHUNK, NEDGES - e0);
  for (int j = tid; j < NB2; j += 256) sh_cnt[j] = 0;
  __syncthreads();
  for (int j = tid; j < n; j += 256) {
    int s = src[e0 + j];
    int d = dst[e0 + j];
    sh_pack[j] = ((unsigned)(d >> 6) << 22) | ((unsigned)s << 6) | (unsigned)(d & 63);
    atomicAdd(&sh_cnt[d >> 6], 1);
  }
  __syncthreads();
  for (int j = tid; j < NB2; j += 256) {
    sh_base[j] = atomicAdd(&bucket_cursor[j], sh_cnt[j]);
    sh_cnt[j] = 0;
  }
  __syncthreads();
  for (int j = tid; j < n; j += 256) {
    unsigned p = sh_pack[j];
    int b = p >> 22;
    int r = atomicAdd(&sh_cnt[b], 1);
    int idx = sh_base[b] + r;
    if (idx < BCAP2) binned[(size_t)b * BCAP2 + idx] = p;
  }
}

// ---------------- weight prep: f32 -> bf16 transposed [c][k], UNswizzled ----------------
__global__ void k_prep(const float* __restrict__ w0_lin, const float* __restrict__ w0_self,
                       const float* __restrict__ w_lin, const float* __restrict__ w_self,
                       const float* __restrict__ w_last, char* __restrict__ wbf) {
  int i = blockIdx.x * 256 + threadIdx.x;  // 0..75775
  float val;
  unsigned byte;
  if (i < 16384) {
    int mat = i >> 13, e = i & 8191, c = e >> 7, k = e & 127;
    byte = mat * 16384 + c * 256 + k * 2;
    val = (mat ? w0_self : w0_lin)[k * 64 + c];
  } else if (i < 57344) {
    int b = i - 16384;
    int lidx = b / 8192, r = b % 8192, mat = r >> 12, e = r & 4095, c = e >> 6, k = e & 63;
    byte = 32768 + lidx * 16384 + mat * 8192 + c * 128 + k * 2;
    val = (mat ? w_self : w_lin)[lidx * 4096 + k * 64 + c];
  } else {
    int b = i - 57344;
    int lidx = b / 3072, r = b % 3072, c = r >> 6, k = r & 63;
    byte = WJK_OFS + lidx * 6144 + c * 128 + k * 2;
    val = (c < OUTF) ? w_last[(lidx * 64 + k) * OUTF + c] : 0.f;
  }
  *(ushort*)(wbf + byte) = f2bf(val);
}

// ---------------- layer-0 transform (x f32 -> z0,s0), B from global ----------------
__global__ __launch_bounds__(256) void k_transform0(
    const float* __restrict__ x, const char* __restrict__ wbf,
    const float* __restrict__ bl, const float* __restrict__ bs, const float* __restrict__ bias,
    ushort* __restrict__ z, ushort* __restrict__ sout) {
  __shared__ alignas(16) char lds[32768];  // A 16K | zst 8K | sst 8K
  int tid = threadIdx.x;
  size_t node0b = (size_t)blockIdx.x * 64;
  for (int q = tid; q < 1024; q += 256) {
    int r = q >> 4, ci = q & 15;
    uint4 v = {0, 0, 0, 0};
    size_t node = node0b + r;
    if (node < NNODES) {
      const float4* sp = (const float4*)(x + node * 128 + ci * 8);
      float4 f0 = sp[0], f1 = sp[1];
      v.x = pack2(f0.x, f0.y); v.y = pack2(f0.z, f0.w);
      v.z = pack2(f1.x, f1.y); v.w = pack2(f1.z, f1.w);
    }
    *(uint4*)(lds + r * 256 + (((unsigned)(ci * 16)) ^ ((r & 7) << 4))) = v;
  }
  __syncthreads();
  int lane = tid & 63, wave = tid >> 6;
  int r0 = lane & 15, kg = lane >> 4;
  int rr = wave * 16 + r0;
  f32x4 az[4], as_[4];
#pragma unroll
  for (int n = 0; n < 4; ++n) { az[n] = (f32x4){0, 0, 0, 0}; as_[n] = (f32x4){0, 0, 0, 0}; }
#pragma unroll
  for (int kk = 0; kk < 4; ++kk) {
    unsigned ak = kk * 64 + kg * 16;
    short8 a = *(const short8*)(lds + rr * 256 + (ak ^ ((rr & 7) << 4)));
#pragma unroll
    for (int n = 0; n < 4; ++n) {
      int c = n * 16 + r0;
      short8 bz = *(const short8*)(wbf + c * 256 + ak);
      short8 bw = *(const short8*)(wbf + 16384 + c * 256 + ak);
      az[n] = __builtin_amdgcn_mfma_f32_16x16x32_bf16(a, bz, az[n], 0, 0, 0);
      as_[n] = __builtin_amdgcn_mfma_f32_16x16x32_bf16(a, bw, as_[n], 0, 0, 0);
    }
  }
  ushort* zst = (ushort*)(lds + 16384);
  ushort* sst = (ushort*)(lds + 24576);
#pragma unroll
  for (int n = 0; n < 4; ++n) {
    int c = n * 16 + r0;
    float cc = bl[c] + bs[c] + bias[c];
#pragma unroll
    for (int j = 0; j < 4; ++j) {
      int rw = wave * 16 + 4 * kg + j;
      zst[rw * 64 + c] = f2bf(az[n][j]);
      sst[rw * 64 + c] = f2bf(as_[n][j] + cc);
    }
  }
  __syncthreads();
  for (int q = tid; q < 512; q += 256) {
    int r = q >> 3;
    if (node0b + r < NNODES) {
      ((uint4*)z)[node0b * 8 + q] = *(const uint4*)(lds + 16384 + q * 16);
      ((uint4*)sout)[node0b * 8 + q] = *(const uint4*)(lds + 24576 + q * 16);
    }
  }
}

// ---------------- fused layer: streaming-atomic aggregate + (JK, next transform) --------
// 512 thr = 8 waves, one 64-node bucket per block. Edge-parallel: waves stream 16-edge
// batches (8 lanes/edge, 2-deep), ds_add_f32 into acc[64][64] (col XOR-swizzled by dst).
// No per-node loop, no shuffle reduce. Then acc+s -> relu -> A-tile -> MFMA phase B.
template <int NEXT, int INIT>
__global__ __launch_bounds__(512) void k_fused(
    const int* __restrict__ bucket_cursor, const unsigned* __restrict__ binned,
    const ushort* __restrict__ z_prev, ushort* __restrict__ s_io,
    const char* __restrict__ wbf, int wl_ofs, int jk_l,
    const float* __restrict__ bl, const float* __restrict__ bs, const float* __restrict__ bias,
    const float* __restrict__ b_last, float* __restrict__ out,
    ushort* __restrict__ z_next) {
  __shared__ alignas(16) float acc[64 * 64];   // 16KB; aliased by zst/sst in epilogue
  __shared__ alignas(16) char atile[8192];
  int tid = threadIdx.x;
  int wave = tid >> 6, lane = tid & 63;
  int g = lane >> 3, fi = lane & 7;
  int b = blockIdx.x;
  int node0 = b * 64;
  int cnt = min(bucket_cursor[b], BCAP2);
  const uint4* zv = (const uint4*)z_prev;
  const unsigned* ebuf = binned + (size_t)b * BCAP2;

  for (int i = tid; i < 1024; i += 512) ((float4*)acc)[i] = make_float4(0.f, 0.f, 0.f, 0.f);
  __syncthreads();

  // ---- streaming aggregate ----
  int cm1 = cnt - 1;
  for (int e0 = wave * 16; e0 < cnt; e0 += 128) {
    int ea = e0 + g, eb2 = e0 + 8 + g;
    unsigned wa = ebuf[min(ea, cm1)];
    unsigned wb = ebuf[min(eb2, cm1)];
    int ia = (ea <= cm1) ? (int)((wa >> 6) & 0xffffu) : ZSENT;
    int ib = (eb2 <= cm1) ? (int)((wb >> 6) & 0xffffu) : ZSENT;
    uint4 v0 = zv[(size_t)ia * 8 + fi];
    uint4 v1 = zv[(size_t)ib * 8 + fi];
    int dla = wa & 63, dlb = wb & 63;
    float* ap = acc + dla * 64 + ((fi * 8) ^ ((dla & 7) << 3));
    float* bp = acc + dlb * 64 + ((fi * 8) ^ ((dlb & 7) << 3));
    float2 p0 = bf2_unpack(v0.x), p1 = bf2_unpack(v0.y), p2 = bf2_unpack(v0.z), p3 = bf2_unpack(v0.w);
    float2 q0 = bf2_unpack(v1.x), q1 = bf2_unpack(v1.y), q2 = bf2_unpack(v1.z), q3 = bf2_unpack(v1.w);
    atomicAdd(ap + 0, p0.x); atomicAdd(ap + 1, p0.y);
    atomicAdd(ap + 2, p1.x); atomicAdd(ap + 3, p1.y);
    atomicAdd(ap + 4, p2.x); atomicAdd(ap + 5, p2.y);
    atomicAdd(ap + 6, p3.x); atomicAdd(ap + 7, p3.y);
    atomicAdd(bp + 0, q0.x); atomicAdd(bp + 1, q0.y);
    atomicAdd(bp + 2, q1.x); atomicAdd(bp + 3, q1.y);
    atomicAdd(bp + 4, q2.x); atomicAdd(bp + 5, q2.y);
    atomicAdd(bp + 6, q3.x); atomicAdd(bp + 7, q3.y);
  }
  __syncthreads();

  // ---- A-tile build: acc + s -> relu -> bf16 swizzled ----
  {
    int r = tid >> 3, f = tid & 7;
    int node = node0 + r;
    const float* ap = acc + r * 64 + ((f * 8) ^ ((r & 7) << 3));
    float4 a0 = ((const float4*)ap)[0], a1 = ((const float4*)ap)[1];
    uint4 sv = {0, 0, 0, 0};
    if (node < NNODES) sv = ((const uint4*)s_io)[(size_t)node * 8 + f];
    float2 s0 = bf2_unpack(sv.x), s1 = bf2_unpack(sv.y), s2 = bf2_unpack(sv.z), s3 = bf2_unpack(sv.w);
    float h0 = fmaxf(a0.x + s0.x, 0.f), h1 = fmaxf(a0.y + s0.y, 0.f);
    float h2 = fmaxf(a0.z + s1.x, 0.f), h3 = fmaxf(a0.w + s1.y, 0.f);
    float h4 = fmaxf(a1.x + s2.x, 0.f), h5 = fmaxf(a1.y + s2.y, 0.f);
    float h6 = fmaxf(a1.z + s3.x, 0.f), h7 = fmaxf(a1.w + s3.y, 0.f);
    uint4 hp;
    hp.x = pack2(h0, h1); hp.y = pack2(h2, h3);
    hp.z = pack2(h4, h5); hp.w = pack2(h6, h7);
    *(uint4*)(atile + r * 128 + (((unsigned)(f * 16)) ^ ((r & 7) << 4))) = hp;
  }
  __syncthreads();

  // ---- phase B: wave (rb = w&3 row-block, ch = w>>2 col-half) ----
  int r0 = lane & 15, kg = lane >> 4;
  int rb = wave & 3, ch = wave >> 2;
  int rr = rb * 16 + r0;
  int nodeBase = node0 + rb * 16;
  f32x4 az0 = {0,0,0,0}, az1 = {0,0,0,0}, as0 = {0,0,0,0}, as1 = {0,0,0,0};
  f32x4 ao0 = {0,0,0,0}, ao1 = {0,0,0,0};
  int c0 = (ch ? 2 : 0) * 16 + r0;   // JK col-block A (ch0: n0; ch1: n2)
  int c1 = 16 + r0;                   // JK col-block B (ch0 only)
  if constexpr (INIT) {
    float bi0 = (c0 < OUTF) ? b_last[c0] : 0.f;
    ao0 = (f32x4){bi0, bi0, bi0, bi0};
    if (ch == 0) { float bi1 = b_last[c1]; ao1 = (f32x4){bi1, bi1, bi1, bi1}; }
  } else {
    if (c0 < OUTF) {
#pragma unroll
      for (int j = 0; j < 4; ++j) {
        int node = nodeBase + 4 * kg + j;
        if (node < NNODES) ao0[j] = out[(size_t)node * OUTF + c0];
      }
    }
    if (ch == 0) {
#pragma unroll
      for (int j = 0; j < 4; ++j) {
        int node = nodeBase + 4 * kg + j;
        if (node < NNODES) ao1[j] = out[(size_t)node * OUTF + c1];
      }
    }
  }
  int cz0 = (ch * 2) * 16 + r0;
  int cz1 = (ch * 2 + 1) * 16 + r0;
#pragma unroll
  for (int kk = 0; kk < 2; ++kk) {
    unsigned ak = kk * 64 + kg * 16;
    short8 a = *(const short8*)(atile + rr * 128 + (ak ^ ((rr & 7) << 4)));
    if constexpr (NEXT) {
      short8 bz0 = *(const short8*)(wbf + wl_ofs + cz0 * 128 + ak);
      short8 bz1 = *(const short8*)(wbf + wl_ofs + cz1 * 128 + ak);
      short8 bw0 = *(const short8*)(wbf + wl_ofs + 8192 + cz0 * 128 + ak);
      short8 bw1 = *(const short8*)(wbf + wl_ofs + 8192 + cz1 * 128 + ak);
      az0 = __builtin_amdgcn_mfma_f32_16x16x32_bf16(a, bz0, az0, 0, 0, 0);
      az1 = __builtin_amdgcn_mfma_f32_16x16x32_bf16(a, bz1, az1, 0, 0, 0);
      as0 = __builtin_amdgcn_mfma_f32_16x16x32_bf16(a, bw0, as0, 0, 0, 0);
      as1 = __builtin_amdgcn_mfma_f32_16x16x32_bf16(a, bw1, as1, 0, 0, 0);
    }
    const char* jkb = wbf + WJK_OFS + jk_l * 6144;
    short8 j0 = *(const short8*)(jkb + c0 * 128 + ak);
    ao0 = __builtin_amdgcn_mfma_f32_16x16x32_bf16(a, j0, ao0, 0, 0, 0);
    if (ch == 0) {
      short8 j1 = *(const short8*)(jkb + c1 * 128 + ak);
      ao1 = __builtin_amdgcn_mfma_f32_16x16x32_bf16(a, j1, ao1, 0, 0, 0);
    }
  }
  if (c0 < OUTF) {
#pragma unroll
    for (int j = 0; j < 4; ++j) {
      int node = nodeBase + 4 * kg + j;
      if (node < NNODES) out[(size_t)node * OUTF + c0] = ao0[j];
    }
  }
  if (ch == 0) {
#pragma unroll
    for (int j = 0; j < 4; ++j) {
      int node = nodeBase + 4 * kg + j;
      if (node < NNODES) out[(size_t)node * OUTF + c1] = ao1[j];
    }
  }
  if constexpr (NEXT) {
    ushort* zst = (ushort*)acc;          // aliases acc (dead after A-build)
    ushort* sst = (ushort*)acc + 4096;
    float cc0 = bl[cz0] + bs[cz0] + bias[cz0];
    float cc1 = bl[cz1] + bs[cz1] + bias[cz1];
#pragma unroll
    for (int j = 0; j < 4; ++j) {
      int rw = rb * 16 + 4 * kg + j;
      zst[rw * 64 + cz0] = f2bf(az0[j]);
      zst[rw * 64 + cz1] = f2bf(az1[j]);
      sst[rw * 64 + cz0] = f2bf(as0[j] + cc0);
      sst[rw * 64 + cz1] = f2bf(as1[j] + cc1);
    }
    __syncthreads();
    if (node0 + (tid >> 3) < NNODES) {
      ((uint4*)z_next)[(size_t)node0 * 8 + tid] = ((const uint4*)zst)[tid];
      ((uint4*)s_io)[(size_t)node0 * 8 + tid] = ((const uint4*)sst)[tid];
    }
  }
}

static inline size_t align16(size_t x) { return (x + 15) & ~(size_t)15; }

extern "C" void kernel_launch(void* const* d_in, const int* in_sizes, int n_in,
                              void* d_out, int out_size, void* d_ws, size_t ws_size,
                              hipStream_t stream) {
  const float* x      = (const float*)d_in[0];
  const int*   src    = (const int*)d_in[1];
  const int*   dst    = (const int*)d_in[2];
  const float* w0_lin = (const float*)d_in[3];
  const float* b0_lin = (const float*)d_in[4];
  const float* w0_self= (const float*)d_in[5];
  const float* b0_self= (const float*)d_in[6];
  const float* bias0  = (const float*)d_in[7];
  const float* w_lin  = (const float*)d_in[8];
  const float* b_lin  = (const float*)d_in[9];
  const float* w_self = (const float*)d_in[10];
  const float* b_self = (const float*)d_in[11];
  const float* bias   = (const float*)d_in[12];
  const float* w_last = (const float*)d_in[13];
  const float* b_last = (const float*)d_in[14];
  float* out = (float*)d_out;

  char* w = (char*)d_ws;
  int* bucket_cursor = (int*)w;  w += align16((size_t)NB2 * 4);
  unsigned* binned   = (unsigned*)w; w += align16((size_t)NB2 * BCAP2 * 4);  // persists all layers
  ushort* zA = (ushort*)w; w += align16((size_t)ZROWS * 64 * 2);
  ushort* zB = (ushort*)w; w += align16((size_t)ZROWS * 64 * 2);
  ushort* s  = (ushort*)w; w += align16((size_t)NNODES * 64 * 2);
  char* wbf = w; w += WBF_BYTES;

  hipMemsetAsync(bucket_cursor, 0, NB2 * 4, stream);
  k_prep<<<296, 256, 0, stream>>>(w0_lin, w0_self, w_lin, w_self, w_last, wbf);
  k_bin<<<NBINB, 256, 0, stream>>>(src, dst, bucket_cursor, binned);
  // zero the sentinel z rows
  hipMemsetAsync(zA + (size_t)ZSENT * 64, 0, 128, stream);
  hipMemsetAsync(zB + (size_t)ZSENT * 64, 0, 128, stream);

  k_transform0<<<NB2, 256, 0, stream>>>(x, wbf, b0_lin, b0_self, bias0, zA, s);

  for (int k = 0; k < NLAYERS; ++k) {
    ushort* zin = (k % 2 == 0) ? zA : zB;
    ushort* zout = (k % 2 == 0) ? zB : zA;
    int wl_ofs = 32768 + k * 16384;  // w_lin[k]/w_self[k] (producing layer k+1), k<=4
    if (k == 0) {
      k_fused<1, 1><<<NB2, 512, 0, stream>>>(bucket_cursor, binned, zin, s, wbf, wl_ofs, k,
                                             b_lin, b_self, bias, b_last, out, zout);
    } else if (k < NLAYERS - 1) {
      k_fused<1, 0><<<NB2, 512, 0, stream>>>(bucket_cursor, binned, zin, s, wbf, wl_ofs, k,
                                             b_lin + (size_t)k * 64, b_self + (size_t)k * 64,
                                             bias + (size_t)k * 64, nullptr, out, zout);
    } else {
      k_fused<0, 0><<<NB2, 512, 0, stream>>>(bucket_cursor, binned, zin, s, wbf, 0, k,
                                             nullptr, nullptr, nullptr, nullptr, out, zout);
    }
  }
}

// Round 12
// 303.695 us; speedup vs baseline: 13.5533x; 13.5533x over previous
//
#include <hip/hip_runtime.h>

#define NNODES 50000
#define NEDGES 1600000
#define INF 128
#define UNITS 64
#define OUTF 40
#define NLAYERS 6
#define NBUCK 196          // ceil(50000/256), bucket = dst >> 8
#define BCAP 9472          // per-bucket capacity (mean 8192, 14 sigma)
#define CHUNK 8192         // edges per k_bin block
#define NBINB ((NEDGES + CHUNK - 1) / CHUNK)  // 196

#define WJK_OFS 114688     // byte offset of JK (w_last) blocks inside wbf
#define WBF_BYTES (114688 + 6 * 6144)

typedef __attribute__((ext_vector_type(8))) short short8;
typedef __attribute__((ext_vector_type(4))) float f32x4;

__device__ __forceinline__ ushort f2bf(float f) {
  unsigned u = __float_as_uint(f);
  unsigned r = (u + 0x7fffu + ((u >> 16) & 1u)) >> 16;
  return (ushort)r;
}
__device__ __forceinline__ unsigned pack2(float a, float b) {
  return ((unsigned)f2bf(b) << 16) | (unsigned)f2bf(a);
}
__device__ __forceinline__ float2 bf2_unpack(unsigned v) {
  float2 r;
  r.x = __uint_as_float(v << 16);
  r.y = __uint_as_float(v & 0xffff0000u);
  return r;
}

// ---------------- CSR build ----------------
__global__ void k_bin(const int* __restrict__ src, const int* __restrict__ dst,
                      int* __restrict__ bucket_cursor, unsigned* __restrict__ binned) {
  __shared__ unsigned sh_pack[CHUNK];
  __shared__ int sh_cnt[NBUCK];
  __shared__ int sh_base[NBUCK];
  int tid = threadIdx.x;
  int e0 = blockIdx.x * CHUNK;
  int n = min(CHUNK, NEDGES - e0);
  for (int j = tid; j < NBUCK; j += 256) sh_cnt[j] = 0;
  __syncthreads();
  for (int j = tid; j < n; j += 256) {
    int s = src[e0 + j];
    int d = dst[e0 + j];
    sh_pack[j] = ((unsigned)(d >> 8) << 24) | ((unsigned)s << 8) | (unsigned)(d & 255);
    atomicAdd(&sh_cnt[d >> 8], 1);
  }
  __syncthreads();
  if (tid < NBUCK) {
    sh_base[tid] = atomicAdd(&bucket_cursor[tid], sh_cnt[tid]);
    sh_cnt[tid] = 0;
  }
  __syncthreads();
  for (int j = tid; j < n; j += 256) {
    unsigned p = sh_pack[j];
    int b = p >> 24;
    int r = atomicAdd(&sh_cnt[b], 1);
    int idx = sh_base[b] + r;
    if (idx < BCAP) binned[(size_t)b * BCAP + idx] = p;
  }
}

__global__ void k_bucket_scan(const int* __restrict__ bucket_cursor,
                              int* __restrict__ bucket_base) {
  __shared__ int sh[256];
  int tid = threadIdx.x;
  int c = (tid < NBUCK) ? min(bucket_cursor[tid], BCAP) : 0;
  sh[tid] = c;
  __syncthreads();
  for (int off = 1; off < 256; off <<= 1) {
    int t = (tid >= off) ? sh[tid - off] : 0;
    __syncthreads();
    sh[tid] += t;
    __syncthreads();
  }
  if (tid < NBUCK) bucket_base[tid] = sh[tid] - c;
}

__global__ void k_build(const int* __restrict__ bucket_cursor, const int* __restrict__ bucket_base,
                        const unsigned* __restrict__ binned, int* __restrict__ row_ptr,
                        ushort* __restrict__ srcs) {
  __shared__ unsigned sh_packed[BCAP];
  __shared__ int sh_cnt[256];
  __shared__ int sh_off[256];
  int tid = threadIdx.x;
  int b = blockIdx.x;
  int cnt = min(bucket_cursor[b], BCAP);
  int base = bucket_base[b];
  for (int i = tid; i < cnt; i += 256) sh_packed[i] = binned[(size_t)b * BCAP + i];
  sh_cnt[tid] = 0;
  __syncthreads();
  for (int i = tid; i < cnt; i += 256) atomicAdd(&sh_cnt[sh_packed[i] & 255], 1);
  __syncthreads();
  int c = sh_cnt[tid];
  sh_off[tid] = c;
  __syncthreads();
  for (int off = 1; off < 256; off <<= 1) {
    int t = (tid >= off) ? sh_off[tid - off] : 0;
    __syncthreads();
    sh_off[tid] += t;
    __syncthreads();
  }
  int excl = sh_off[tid] - c;
  int node = b * 256 + tid;
  if (node <= NNODES) row_ptr[node] = base + excl;
  sh_off[tid] = excl;
  __syncthreads();
  for (int i = tid; i < cnt; i += 256) {
    unsigned p = sh_packed[i];
    int dl = p & 255;
    int pos = atomicAdd(&sh_off[dl], 1);
    srcs[base + pos] = (ushort)((p >> 8) & 0xffff);
  }
}

// ---------------- weight prep: f32 -> bf16 transposed [c][k], UNswizzled ----------------
__global__ void k_prep(const float* __restrict__ w0_lin, const float* __restrict__ w0_self,
                       const float* __restrict__ w_lin, const float* __restrict__ w_self,
                       const float* __restrict__ w_last, char* __restrict__ wbf) {
  int i = blockIdx.x * 256 + threadIdx.x;  // 0..75775
  float val;
  unsigned byte;
  if (i < 16384) {
    int mat = i >> 13, e = i & 8191, c = e >> 7, k = e & 127;
    byte = mat * 16384 + c * 256 + k * 2;
    val = (mat ? w0_self : w0_lin)[k * 64 + c];
  } else if (i < 57344) {
    int b = i - 16384;
    int lidx = b / 8192, r = b % 8192, mat = r >> 12, e = r & 4095, c = e >> 6, k = e & 63;
    byte = 32768 + lidx * 16384 + mat * 8192 + c * 128 + k * 2;
    val = (mat ? w_self : w_lin)[lidx * 4096 + k * 64 + c];
  } else {
    int b = i - 57344;
    int lidx = b / 3072, r = b % 3072, c = r >> 6, k = r & 63;
    byte = WJK_OFS + lidx * 6144 + c * 128 + k * 2;
    val = (c < OUTF) ? w_last[(lidx * 64 + k) * OUTF + c] : 0.f;
  }
  *(ushort*)(wbf + byte) = f2bf(val);
}

// ---------------- layer-0 transform (x f32 -> z0,s0), B from global ----------------
__global__ __launch_bounds__(256) void k_transform0(
    const float* __restrict__ x, const char* __restrict__ wbf,
    const float* __restrict__ bl, const float* __restrict__ bs, const float* __restrict__ bias,
    ushort* __restrict__ z, ushort* __restrict__ sout) {
  __shared__ alignas(16) char lds[32768];  // A 16K | zst 8K | sst 8K
  int tid = threadIdx.x;
  size_t node0b = (size_t)blockIdx.x * 64;
  for (int q = tid; q < 1024; q += 256) {
    int r = q >> 4, ci = q & 15;
    uint4 v = {0, 0, 0, 0};
    size_t node = node0b + r;
    if (node < NNODES) {
      const float4* sp = (const float4*)(x + node * 128 + ci * 8);
      float4 f0 = sp[0], f1 = sp[1];
      v.x = pack2(f0.x, f0.y); v.y = pack2(f0.z, f0.w);
      v.z = pack2(f1.x, f1.y); v.w = pack2(f1.z, f1.w);
    }
    *(uint4*)(lds + r * 256 + (((unsigned)(ci * 16)) ^ ((r & 7) << 4))) = v;
  }
  __syncthreads();
  int lane = tid & 63, wave = tid >> 6;
  int r0 = lane & 15, kg = lane >> 4;
  int rr = wave * 16 + r0;
  f32x4 az[4], as_[4];
#pragma unroll
  for (int n = 0; n < 4; ++n) { az[n] = (f32x4){0, 0, 0, 0}; as_[n] = (f32x4){0, 0, 0, 0}; }
#pragma unroll
  for (int kk = 0; kk < 4; ++kk) {
    unsigned ak = kk * 64 + kg * 16;
    short8 a = *(const short8*)(lds + rr * 256 + (ak ^ ((rr & 7) << 4)));
#pragma unroll
    for (int n = 0; n < 4; ++n) {
      int c = n * 16 + r0;
      short8 bz = *(const short8*)(wbf + c * 256 + ak);
      short8 bw = *(const short8*)(wbf + 16384 + c * 256 + ak);
      az[n] = __builtin_amdgcn_mfma_f32_16x16x32_bf16(a, bz, az[n], 0, 0, 0);
      as_[n] = __builtin_amdgcn_mfma_f32_16x16x32_bf16(a, bw, as_[n], 0, 0, 0);
    }
  }
  ushort* zst = (ushort*)(lds + 16384);
  ushort* sst = (ushort*)(lds + 24576);
#pragma unroll
  for (int n = 0; n < 4; ++n) {
    int c = n * 16 + r0;
    float cc = bl[c] + bs[c] + bias[c];
#pragma unroll
    for (int j = 0; j < 4; ++j) {
      int rw = wave * 16 + 4 * kg + j;
      zst[rw * 64 + c] = f2bf(az[n][j]);
      sst[rw * 64 + c] = f2bf(as_[n][j] + cc);
    }
  }
  __syncthreads();
  for (int q = tid; q < 512; q += 256) {
    int r = q >> 3;
    if (node0b + r < NNODES) {
      ((uint4*)z)[node0b * 8 + q] = *(const uint4*)(lds + 16384 + q * 16);
      ((uint4*)sout)[node0b * 8 + q] = *(const uint4*)(lds + 24576 + q * 16);
    }
  }
}

// ---------------- fused layer: aggregate + (JK, next transform) ----------------
// R6 structure (best known). Two critical-path trims: (1) s-row load hoisted above
// the gather loop (was inside if(g==0) AFTER the shuffle reduce); (2) next node's
// first srcs word prefetched (L1-warm) during this node's gathers. srcs padded +16.
template <int NEXT, int INIT>
__global__ __launch_bounds__(256) void k_fused(
    const int* __restrict__ row_ptr, const ushort* __restrict__ srcs,
    const ushort* __restrict__ z_prev, const ushort* __restrict__ s_io,
    const char* __restrict__ wbf, int wl_ofs, int jk_l,
    const float* __restrict__ bl, const float* __restrict__ bs, const float* __restrict__ bias,
    const float* __restrict__ b_last, float* __restrict__ out,
    ushort* __restrict__ z_next) {
  __shared__ alignas(16) char lds[NEXT ? 6144 : 2048];  // A 2K | zst 2K | sst 2K
  int tid = threadIdx.x;
  int wave = tid >> 6, lane = tid & 63;
  int g = lane >> 3, fi = lane & 7;
  int base = blockIdx.x * 16;
  const uint4* zv = (const uint4*)z_prev;

  // ---- phase A ----
  for (int q = 0; q < 4; ++q) {
    int node = base + wave * 4 + q;
    int st = row_ptr[node];
    int en = row_ptr[node + 1];
    // (1) hoist: s row load issues before the gathers, not after the reduce
    uint4 sv4 = ((const uint4*)s_io)[(size_t)node * 8 + fi];
    // (2) prefetch next node's first srcs word (st_{q+1} == en); padded buffer
    if (q < 3) {
      ushort pf = srcs[en + g];
      asm volatile("" :: "v"((int)pf));
    }
    float a0 = 0, a1 = 0, a2 = 0, a3 = 0, a4 = 0, a5 = 0, a6 = 0, a7 = 0;
    int e = st + g;
    for (; e + 8 < en; e += 16) {
      int i0 = srcs[e];
      int i1 = srcs[e + 8];
      uint4 v0 = zv[(size_t)i0 * 8 + fi];
      uint4 v1 = zv[(size_t)i1 * 8 + fi];
      float2 p0 = bf2_unpack(v0.x), p1 = bf2_unpack(v0.y), p2 = bf2_unpack(v0.z), p3 = bf2_unpack(v0.w);
      float2 q0 = bf2_unpack(v1.x), q1 = bf2_unpack(v1.y), q2 = bf2_unpack(v1.z), q3 = bf2_unpack(v1.w);
      a0 += p0.x + q0.x; a1 += p0.y + q0.y;
      a2 += p1.x + q1.x; a3 += p1.y + q1.y;
      a4 += p2.x + q2.x; a5 += p2.y + q2.y;
      a6 += p3.x + q3.x; a7 += p3.y + q3.y;
    }
    if (e < en) {
      uint4 v = zv[(size_t)srcs[e] * 8 + fi];
      float2 p0 = bf2_unpack(v.x), p1 = bf2_unpack(v.y), p2 = bf2_unpack(v.z), p3 = bf2_unpack(v.w);
      a0 += p0.x; a1 += p0.y; a2 += p1.x; a3 += p1.y;
      a4 += p2.x; a5 += p2.y; a6 += p3.x; a7 += p3.y;
    }
#pragma unroll
    for (int m = 8; m < 64; m <<= 1) {
      a0 += __shfl_xor(a0, m); a1 += __shfl_xor(a1, m);
      a2 += __shfl_xor(a2, m); a3 += __shfl_xor(a3, m);
      a4 += __shfl_xor(a4, m); a5 += __shfl_xor(a5, m);
      a6 += __shfl_xor(a6, m); a7 += __shfl_xor(a7, m);
    }
    if (g == 0) {
      float2 s0 = bf2_unpack(sv4.x), s1 = bf2_unpack(sv4.y), s2 = bf2_unpack(sv4.z), s3 = bf2_unpack(sv4.w);
      float h0 = fmaxf(a0 + s0.x, 0.f), h1 = fmaxf(a1 + s0.y, 0.f);
      float h2 = fmaxf(a2 + s1.x, 0.f), h3 = fmaxf(a3 + s1.y, 0.f);
      float h4 = fmaxf(a4 + s2.x, 0.f), h5 = fmaxf(a5 + s2.y, 0.f);
      float h6 = fmaxf(a6 + s3.x, 0.f), h7 = fmaxf(a7 + s3.y, 0.f);
      int r = wave * 4 + q;
      uint4 hp;
      hp.x = pack2(h0, h1); hp.y = pack2(h2, h3);
      hp.z = pack2(h4, h5); hp.w = pack2(h6, h7);
      *(uint4*)(lds + r * 128 + (((unsigned)(fi * 16)) ^ ((r & 7) << 4))) = hp;
    }
  }
  __syncthreads();

  // ---- phase B ----
  int r0 = lane & 15, kg = lane >> 4;
  int c = wave * 16 + r0;
  f32x4 az = {0, 0, 0, 0}, as_ = {0, 0, 0, 0}, ao = {0, 0, 0, 0};
  if (wave < 3) {
    if constexpr (INIT) {
      float bi = (c < OUTF) ? b_last[c] : 0.f;
      ao = (f32x4){bi, bi, bi, bi};
    } else {
      if (c < OUTF) {
#pragma unroll
        for (int j = 0; j < 4; ++j) ao[j] = out[(size_t)(base + 4 * kg + j) * OUTF + c];
      }
    }
  }
#pragma unroll
  for (int kk = 0; kk < 2; ++kk) {
    unsigned ak = kk * 64 + kg * 16;
    short8 a = *(const short8*)(lds + r0 * 128 + (ak ^ ((r0 & 7) << 4)));
    if constexpr (NEXT) {
      short8 bz = *(const short8*)(wbf + wl_ofs + c * 128 + ak);
      short8 bw = *(const short8*)(wbf + wl_ofs + 8192 + c * 128 + ak);
      az = __builtin_amdgcn_mfma_f32_16x16x32_bf16(a, bz, az, 0, 0, 0);
      as_ = __builtin_amdgcn_mfma_f32_16x16x32_bf16(a, bw, as_, 0, 0, 0);
    }
    if (wave < 3) {
      short8 bj = *(const short8*)(wbf + WJK_OFS + jk_l * 6144 + c * 128 + ak);
      ao = __builtin_amdgcn_mfma_f32_16x16x32_bf16(a, bj, ao, 0, 0, 0);
    }
  }
  if (wave < 3 && c < OUTF) {
#pragma unroll
    for (int j = 0; j < 4; ++j) out[(size_t)(base + 4 * kg + j) * OUTF + c] = ao[j];
  }
  if constexpr (NEXT) {
    ushort* zst = (ushort*)(lds + 2048);
    ushort* sst = (ushort*)(lds + 4096);
    float cc = bl[c] + bs[c] + bias[c];
#pragma unroll
    for (int j = 0; j < 4; ++j) {
      int rw = 4 * kg + j;
      zst[rw * 64 + c] = f2bf(az[j]);
      sst[rw * 64 + c] = f2bf(as_[j] + cc);
    }
    __syncthreads();
    if (tid < 128) {
      ((uint4*)z_next)[(size_t)base * 8 + tid] = *(const uint4*)(lds + 2048 + tid * 16);
    } else {
      int q = tid - 128;
      ((uint4*)s_io)[(size_t)base * 8 + q] = *(const uint4*)(lds + 4096 + q * 16);
    }
  }
}

static inline size_t align16(size_t x) { return (x + 15) & ~(size_t)15; }

extern "C" void kernel_launch(void* const* d_in, const int* in_sizes, int n_in,
                              void* d_out, int out_size, void* d_ws, size_t ws_size,
                              hipStream_t stream) {
  const float* x      = (const float*)d_in[0];
  const int*   src    = (const int*)d_in[1];
  const int*   dst    = (const int*)d_in[2];
  const float* w0_lin = (const float*)d_in[3];
  const float* b0_lin = (const float*)d_in[4];
  const float* w0_self= (const float*)d_in[5];
  const float* b0_self= (const float*)d_in[6];
  const float* bias0  = (const float*)d_in[7];
  const float* w_lin  = (const float*)d_in[8];
  const float* b_lin  = (const float*)d_in[9];
  const float* w_self = (const float*)d_in[10];
  const float* b_self = (const float*)d_in[11];
  const float* bias   = (const float*)d_in[12];
  const float* w_last = (const float*)d_in[13];
  const float* b_last = (const float*)d_in[14];
  float* out = (float*)d_out;

  char* w = (char*)d_ws;
  int* row_ptr       = (int*)w;  w += align16((size_t)(NNODES + 1) * 4);
  int* bucket_cursor = (int*)w;  w += align16((size_t)NBUCK * 4);
  int* bucket_base   = (int*)w;  w += align16(1024);
  ushort* srcs       = (ushort*)w; w += align16((size_t)(NEDGES + 16) * 2);  // +16 pad for prefetch
  // binned (7.43 MB) aliases zA+zB (12.8 MB); binned dead before transform0 writes zA.
  char* zbase = w;
  ushort* zA = (ushort*)zbase;
  ushort* zB = (ushort*)(zbase + (size_t)NNODES * 64 * 2);
  unsigned* binned = (unsigned*)zbase;
  w += (size_t)NNODES * 64 * 2 * 2;
  ushort* s = (ushort*)w; w += (size_t)NNODES * 64 * 2;
  char* wbf = w; w += WBF_BYTES;

  hipMemsetAsync(bucket_cursor, 0, NBUCK * 4, stream);
  k_prep<<<296, 256, 0, stream>>>(w0_lin, w0_self, w_lin, w_self, w_last, wbf);
  k_bin<<<NBINB, 256, 0, stream>>>(src, dst, bucket_cursor, binned);
  k_bucket_scan<<<1, 256, 0, stream>>>(bucket_cursor, bucket_base);
  k_build<<<NBUCK, 256, 0, stream>>>(bucket_cursor, bucket_base, binned, row_ptr, srcs);

  k_transform0<<<(NNODES + 63) / 64, 256, 0, stream>>>(x, wbf, b0_lin, b0_self, bias0, zA, s);

  const int FGRID = NNODES / 16;  // 3125
  for (int k = 0; k < NLAYERS; ++k) {
    ushort* zin = (k % 2 == 0) ? zA : zB;
    ushort* zout = (k % 2 == 0) ? zB : zA;
    int wl_ofs = 32768 + k * 16384;  // w_lin[k]/w_self[k] (producing layer k+1), k<=4
    if (k == 0) {
      k_fused<1, 1><<<FGRID, 256, 0, stream>>>(row_ptr, srcs, zin, s, wbf, wl_ofs, k,
                                               b_lin, b_self, bias, b_last, out, zout);
    } else if (k < NLAYERS - 1) {
      k_fused<1, 0><<<FGRID, 256, 0, stream>>>(row_ptr, srcs, zin, s, wbf, wl_ofs, k,
                                               b_lin + (size_t)k * 64, b_self + (size_t)k * 64,
                                               bias + (size_t)k * 64, nullptr, out, zout);
    } else {
      k_fused<0, 0><<<FGRID, 256, 0, stream>>>(row_ptr, srcs, zin, s, wbf, 0, k,
                                               nullptr, nullptr, nullptr, nullptr, out, zout);
    }
  }
}

// Round 13
// 302.263 us; speedup vs baseline: 13.6175x; 1.0047x over previous
//
#include <hip/hip_runtime.h>

#define NNODES 50000
#define NEDGES 1600000
#define INF 128
#define UNITS 64
#define OUTF 40
#define NLAYERS 6
#define NBUCK 196          // ceil(50000/256), bucket = dst >> 8
#define BCAP 9472          // per-bucket capacity (mean 8192, 14 sigma)
#define CHUNK 8192         // edges per k_bin block
#define NBINB ((NEDGES + CHUNK - 1) / CHUNK)  // 196

#define WJK_OFS 114688     // byte offset of JK (w_last) blocks inside wbf
#define WBF_BYTES (114688 + 6 * 6144)

typedef __attribute__((ext_vector_type(8))) short short8;
typedef __attribute__((ext_vector_type(4))) float f32x4;

__device__ __forceinline__ ushort f2bf(float f) {
  unsigned u = __float_as_uint(f);
  unsigned r = (u + 0x7fffu + ((u >> 16) & 1u)) >> 16;
  return (ushort)r;
}
__device__ __forceinline__ unsigned pack2(float a, float b) {
  return ((unsigned)f2bf(b) << 16) | (unsigned)f2bf(a);
}
__device__ __forceinline__ float2 bf2_unpack(unsigned v) {
  float2 r;
  r.x = __uint_as_float(v << 16);
  r.y = __uint_as_float(v & 0xffff0000u);
  return r;
}

// ---------------- CSR build ----------------
__global__ void k_bin(const int* __restrict__ src, const int* __restrict__ dst,
                      int* __restrict__ bucket_cursor, unsigned* __restrict__ binned) {
  __shared__ unsigned sh_pack[CHUNK];
  __shared__ int sh_cnt[NBUCK];
  __shared__ int sh_base[NBUCK];
  int tid = threadIdx.x;
  int e0 = blockIdx.x * CHUNK;
  int n = min(CHUNK, NEDGES - e0);
  for (int j = tid; j < NBUCK; j += 256) sh_cnt[j] = 0;
  __syncthreads();
  for (int j = tid; j < n; j += 256) {
    int s = src[e0 + j];
    int d = dst[e0 + j];
    sh_pack[j] = ((unsigned)(d >> 8) << 24) | ((unsigned)s << 8) | (unsigned)(d & 255);
    atomicAdd(&sh_cnt[d >> 8], 1);
  }
  __syncthreads();
  if (tid < NBUCK) {
    sh_base[tid] = atomicAdd(&bucket_cursor[tid], sh_cnt[tid]);
    sh_cnt[tid] = 0;
  }
  __syncthreads();
  for (int j = tid; j < n; j += 256) {
    unsigned p = sh_pack[j];
    int b = p >> 24;
    int r = atomicAdd(&sh_cnt[b], 1);
    int idx = sh_base[b] + r;
    if (idx < BCAP) binned[(size_t)b * BCAP + idx] = p;
  }
}

__global__ void k_bucket_scan(const int* __restrict__ bucket_cursor,
                              int* __restrict__ bucket_base) {
  __shared__ int sh[256];
  int tid = threadIdx.x;
  int c = (tid < NBUCK) ? min(bucket_cursor[tid], BCAP) : 0;
  sh[tid] = c;
  __syncthreads();
  for (int off = 1; off < 256; off <<= 1) {
    int t = (tid >= off) ? sh[tid - off] : 0;
    __syncthreads();
    sh[tid] += t;
    __syncthreads();
  }
  if (tid < NBUCK) bucket_base[tid] = sh[tid] - c;
}

__global__ void k_build(const int* __restrict__ bucket_cursor, const int* __restrict__ bucket_base,
                        const unsigned* __restrict__ binned, int* __restrict__ row_ptr,
                        ushort* __restrict__ srcs) {
  __shared__ unsigned sh_packed[BCAP];
  __shared__ int sh_cnt[256];
  __shared__ int sh_off[256];
  int tid = threadIdx.x;
  int b = blockIdx.x;
  int cnt = min(bucket_cursor[b], BCAP);
  int base = bucket_base[b];
  for (int i = tid; i < cnt; i += 256) sh_packed[i] = binned[(size_t)b * BCAP + i];
  sh_cnt[tid] = 0;
  __syncthreads();
  for (int i = tid; i < cnt; i += 256) atomicAdd(&sh_cnt[sh_packed[i] & 255], 1);
  __syncthreads();
  int c = sh_cnt[tid];
  sh_off[tid] = c;
  __syncthreads();
  for (int off = 1; off < 256; off <<= 1) {
    int t = (tid >= off) ? sh_off[tid - off] : 0;
    __syncthreads();
    sh_off[tid] += t;
    __syncthreads();
  }
  int excl = sh_off[tid] - c;
  int node = b * 256 + tid;
  if (node <= NNODES) row_ptr[node] = base + excl;
  sh_off[tid] = excl;
  __syncthreads();
  for (int i = tid; i < cnt; i += 256) {
    unsigned p = sh_packed[i];
    int dl = p & 255;
    int pos = atomicAdd(&sh_off[dl], 1);
    srcs[base + pos] = (ushort)((p >> 8) & 0xffff);
  }
}

// ---------------- weight prep: f32 -> bf16 transposed [c][k], UNswizzled ----------------
__global__ void k_prep(const float* __restrict__ w0_lin, const float* __restrict__ w0_self,
                       const float* __restrict__ w_lin, const float* __restrict__ w_self,
                       const float* __restrict__ w_last, char* __restrict__ wbf) {
  int i = blockIdx.x * 256 + threadIdx.x;  // 0..75775
  float val;
  unsigned byte;
  if (i < 16384) {
    int mat = i >> 13, e = i & 8191, c = e >> 7, k = e & 127;
    byte = mat * 16384 + c * 256 + k * 2;
    val = (mat ? w0_self : w0_lin)[k * 64 + c];
  } else if (i < 57344) {
    int b = i - 16384;
    int lidx = b / 8192, r = b % 8192, mat = r >> 12, e = r & 4095, c = e >> 6, k = e & 63;
    byte = 32768 + lidx * 16384 + mat * 8192 + c * 128 + k * 2;
    val = (mat ? w_self : w_lin)[lidx * 4096 + k * 64 + c];
  } else {
    int b = i - 57344;
    int lidx = b / 3072, r = b % 3072, c = r >> 6, k = r & 63;
    byte = WJK_OFS + lidx * 6144 + c * 128 + k * 2;
    val = (c < OUTF) ? w_last[(lidx * 64 + k) * OUTF + c] : 0.f;
  }
  *(ushort*)(wbf + byte) = f2bf(val);
}

// ---------------- layer-0 transform (x f32 -> z0,s0), B from global ----------------
__global__ __launch_bounds__(256) void k_transform0(
    const float* __restrict__ x, const char* __restrict__ wbf,
    const float* __restrict__ bl, const float* __restrict__ bs, const float* __restrict__ bias,
    ushort* __restrict__ z, ushort* __restrict__ sout) {
  __shared__ alignas(16) char lds[32768];  // A 16K | zst 8K | sst 8K
  int tid = threadIdx.x;
  size_t node0b = (size_t)blockIdx.x * 64;
  for (int q = tid; q < 1024; q += 256) {
    int r = q >> 4, ci = q & 15;
    uint4 v = {0, 0, 0, 0};
    size_t node = node0b + r;
    if (node < NNODES) {
      const float4* sp = (const float4*)(x + node * 128 + ci * 8);
      float4 f0 = sp[0], f1 = sp[1];
      v.x = pack2(f0.x, f0.y); v.y = pack2(f0.z, f0.w);
      v.z = pack2(f1.x, f1.y); v.w = pack2(f1.z, f1.w);
    }
    *(uint4*)(lds + r * 256 + (((unsigned)(ci * 16)) ^ ((r & 7) << 4))) = v;
  }
  __syncthreads();
  int lane = tid & 63, wave = tid >> 6;
  int r0 = lane & 15, kg = lane >> 4;
  int rr = wave * 16 + r0;
  f32x4 az[4], as_[4];
#pragma unroll
  for (int n = 0; n < 4; ++n) { az[n] = (f32x4){0, 0, 0, 0}; as_[n] = (f32x4){0, 0, 0, 0}; }
#pragma unroll
  for (int kk = 0; kk < 4; ++kk) {
    unsigned ak = kk * 64 + kg * 16;
    short8 a = *(const short8*)(lds + rr * 256 + (ak ^ ((rr & 7) << 4)));
#pragma unroll
    for (int n = 0; n < 4; ++n) {
      int c = n * 16 + r0;
      short8 bz = *(const short8*)(wbf + c * 256 + ak);
      short8 bw = *(const short8*)(wbf + 16384 + c * 256 + ak);
      az[n] = __builtin_amdgcn_mfma_f32_16x16x32_bf16(a, bz, az[n], 0, 0, 0);
      as_[n] = __builtin_amdgcn_mfma_f32_16x16x32_bf16(a, bw, as_[n], 0, 0, 0);
    }
  }
  ushort* zst = (ushort*)(lds + 16384);
  ushort* sst = (ushort*)(lds + 24576);
#pragma unroll
  for (int n = 0; n < 4; ++n) {
    int c = n * 16 + r0;
    float cc = bl[c] + bs[c] + bias[c];
#pragma unroll
    for (int j = 0; j < 4; ++j) {
      int rw = wave * 16 + 4 * kg + j;
      zst[rw * 64 + c] = f2bf(az[n][j]);
      sst[rw * 64 + c] = f2bf(as_[n][j] + cc);
    }
  }
  __syncthreads();
  for (int q = tid; q < 512; q += 256) {
    int r = q >> 3;
    if (node0b + r < NNODES) {
      ((uint4*)z)[node0b * 8 + q] = *(const uint4*)(lds + 16384 + q * 16);
      ((uint4*)sout)[node0b * 8 + q] = *(const uint4*)(lds + 24576 + q * 16);
    }
  }
}

// ---------------- fused layer: aggregate + (JK, next transform) ----------------
// R12 structure (best known): R6 gather + hoisted s load + srcs prefetch.
template <int NEXT, int INIT>
__global__ __launch_bounds__(256) void k_fused(
    const int* __restrict__ row_ptr, const ushort* __restrict__ srcs,
    const ushort* __restrict__ z_prev, const ushort* __restrict__ s_io,
    const char* __restrict__ wbf, int wl_ofs, int jk_l,
    const float* __restrict__ bl, const float* __restrict__ bs, const float* __restrict__ bias,
    const float* __restrict__ b_last, float* __restrict__ out,
    ushort* __restrict__ z_next) {
  __shared__ alignas(16) char lds[NEXT ? 6144 : 2048];  // A 2K | zst 2K | sst 2K
  int tid = threadIdx.x;
  int wave = tid >> 6, lane = tid & 63;
  int g = lane >> 3, fi = lane & 7;
  int base = blockIdx.x * 16;
  const uint4* zv = (const uint4*)z_prev;

  // ---- phase A ----
  for (int q = 0; q < 4; ++q) {
    int node = base + wave * 4 + q;
    int st = row_ptr[node];
    int en = row_ptr[node + 1];
    // hoist: s row load issues before the gathers, not after the reduce
    uint4 sv4 = ((const uint4*)s_io)[(size_t)node * 8 + fi];
    // prefetch next node's first srcs word (st_{q+1} == en); padded buffer
    if (q < 3) {
      ushort pf = srcs[en + g];
      asm volatile("" :: "v"((int)pf));
    }
    float a0 = 0, a1 = 0, a2 = 0, a3 = 0, a4 = 0, a5 = 0, a6 = 0, a7 = 0;
    int e = st + g;
    for (; e + 8 < en; e += 16) {
      int i0 = srcs[e];
      int i1 = srcs[e + 8];
      uint4 v0 = zv[(size_t)i0 * 8 + fi];
      uint4 v1 = zv[(size_t)i1 * 8 + fi];
      float2 p0 = bf2_unpack(v0.x), p1 = bf2_unpack(v0.y), p2 = bf2_unpack(v0.z), p3 = bf2_unpack(v0.w);
      float2 q0 = bf2_unpack(v1.x), q1 = bf2_unpack(v1.y), q2 = bf2_unpack(v1.z), q3 = bf2_unpack(v1.w);
      a0 += p0.x + q0.x; a1 += p0.y + q0.y;
      a2 += p1.x + q1.x; a3 += p1.y + q1.y;
      a4 += p2.x + q2.x; a5 += p2.y + q2.y;
      a6 += p3.x + q3.x; a7 += p3.y + q3.y;
    }
    if (e < en) {
      uint4 v = zv[(size_t)srcs[e] * 8 + fi];
      float2 p0 = bf2_unpack(v.x), p1 = bf2_unpack(v.y), p2 = bf2_unpack(v.z), p3 = bf2_unpack(v.w);
      a0 += p0.x; a1 += p0.y; a2 += p1.x; a3 += p1.y;
      a4 += p2.x; a5 += p2.y; a6 += p3.x; a7 += p3.y;
    }
#pragma unroll
    for (int m = 8; m < 64; m <<= 1) {
      a0 += __shfl_xor(a0, m); a1 += __shfl_xor(a1, m);
      a2 += __shfl_xor(a2, m); a3 += __shfl_xor(a3, m);
      a4 += __shfl_xor(a4, m); a5 += __shfl_xor(a5, m);
      a6 += __shfl_xor(a6, m); a7 += __shfl_xor(a7, m);
    }
    if (g == 0) {
      float2 s0 = bf2_unpack(sv4.x), s1 = bf2_unpack(sv4.y), s2 = bf2_unpack(sv4.z), s3 = bf2_unpack(sv4.w);
      float h0 = fmaxf(a0 + s0.x, 0.f), h1 = fmaxf(a1 + s0.y, 0.f);
      float h2 = fmaxf(a2 + s1.x, 0.f), h3 = fmaxf(a3 + s1.y, 0.f);
      float h4 = fmaxf(a4 + s2.x, 0.f), h5 = fmaxf(a5 + s2.y, 0.f);
      float h6 = fmaxf(a6 + s3.x, 0.f), h7 = fmaxf(a7 + s3.y, 0.f);
      int r = wave * 4 + q;
      uint4 hp;
      hp.x = pack2(h0, h1); hp.y = pack2(h2, h3);
      hp.z = pack2(h4, h5); hp.w = pack2(h6, h7);
      *(uint4*)(lds + r * 128 + (((unsigned)(fi * 16)) ^ ((r & 7) << 4))) = hp;
    }
  }
  __syncthreads();

  // ---- phase B ----
  int r0 = lane & 15, kg = lane >> 4;
  int c = wave * 16 + r0;
  f32x4 az = {0, 0, 0, 0}, as_ = {0, 0, 0, 0}, ao = {0, 0, 0, 0};
  if (wave < 3) {
    if constexpr (INIT) {
      float bi = (c < OUTF) ? b_last[c] : 0.f;
      ao = (f32x4){bi, bi, bi, bi};
    } else {
      if (c < OUTF) {
#pragma unroll
        for (int j = 0; j < 4; ++j) ao[j] = out[(size_t)(base + 4 * kg + j) * OUTF + c];
      }
    }
  }
#pragma unroll
  for (int kk = 0; kk < 2; ++kk) {
    unsigned ak = kk * 64 + kg * 16;
    short8 a = *(const short8*)(lds + r0 * 128 + (ak ^ ((r0 & 7) << 4)));
    if constexpr (NEXT) {
      short8 bz = *(const short8*)(wbf + wl_ofs + c * 128 + ak);
      short8 bw = *(const short8*)(wbf + wl_ofs + 8192 + c * 128 + ak);
      az = __builtin_amdgcn_mfma_f32_16x16x32_bf16(a, bz, az, 0, 0, 0);
      as_ = __builtin_amdgcn_mfma_f32_16x16x32_bf16(a, bw, as_, 0, 0, 0);
    }
    if (wave < 3) {
      short8 bj = *(const short8*)(wbf + WJK_OFS + jk_l * 6144 + c * 128 + ak);
      ao = __builtin_amdgcn_mfma_f32_16x16x32_bf16(a, bj, ao, 0, 0, 0);
    }
  }
  if (wave < 3 && c < OUTF) {
#pragma unroll
    for (int j = 0; j < 4; ++j) out[(size_t)(base + 4 * kg + j) * OUTF + c] = ao[j];
  }
  if constexpr (NEXT) {
    ushort* zst = (ushort*)(lds + 2048);
    ushort* sst = (ushort*)(lds + 4096);
    float cc = bl[c] + bs[c] + bias[c];
#pragma unroll
    for (int j = 0; j < 4; ++j) {
      int rw = 4 * kg + j;
      zst[rw * 64 + c] = f2bf(az[j]);
      sst[rw * 64 + c] = f2bf(as_[j] + cc);
    }
    __syncthreads();
    if (tid < 128) {
      ((uint4*)z_next)[(size_t)base * 8 + tid] = *(const uint4*)(lds + 2048 + tid * 16);
    } else {
      int q = tid - 128;
      ((uint4*)s_io)[(size_t)base * 8 + q] = *(const uint4*)(lds + 4096 + q * 16);
    }
  }
}

// 256-byte alignment: z/s rows are 128 B — align16 left zbase ≡16 (mod 128), making
// every gathered row straddle 3 cache lines instead of 2 (R12 audit).
static inline size_t align256(size_t x) { return (x + 255) & ~(size_t)255; }

extern "C" void kernel_launch(void* const* d_in, const int* in_sizes, int n_in,
                              void* d_out, int out_size, void* d_ws, size_t ws_size,
                              hipStream_t stream) {
  const float* x      = (const float*)d_in[0];
  const int*   src    = (const int*)d_in[1];
  const int*   dst    = (const int*)d_in[2];
  const float* w0_lin = (const float*)d_in[3];
  const float* b0_lin = (const float*)d_in[4];
  const float* w0_self= (const float*)d_in[5];
  const float* b0_self= (const float*)d_in[6];
  const float* bias0  = (const float*)d_in[7];
  const float* w_lin  = (const float*)d_in[8];
  const float* b_lin  = (const float*)d_in[9];
  const float* w_self = (const float*)d_in[10];
  const float* b_self = (const float*)d_in[11];
  const float* bias   = (const float*)d_in[12];
  const float* w_last = (const float*)d_in[13];
  const float* b_last = (const float*)d_in[14];
  float* out = (float*)d_out;

  char* w = (char*)d_ws;
  int* row_ptr       = (int*)w;  w += align256((size_t)(NNODES + 1) * 4);
  int* bucket_cursor = (int*)w;  w += align256((size_t)NBUCK * 4);
  int* bucket_base   = (int*)w;  w += align256(1024);
  ushort* srcs       = (ushort*)w; w += align256((size_t)(NEDGES + 16) * 2);  // +16 pad for prefetch
  // binned (7.43 MB) aliases zA+zB (12.8 MB); binned dead before transform0 writes zA.
  char* zbase = w;
  ushort* zA = (ushort*)zbase;
  ushort* zB = (ushort*)(zbase + (size_t)NNODES * 64 * 2);
  unsigned* binned = (unsigned*)zbase;
  w += (size_t)NNODES * 64 * 2 * 2;
  ushort* s = (ushort*)w; w += (size_t)NNODES * 64 * 2;
  char* wbf = w; w += WBF_BYTES;

  hipMemsetAsync(bucket_cursor, 0, NBUCK * 4, stream);
  k_prep<<<296, 256, 0, stream>>>(w0_lin, w0_self, w_lin, w_self, w_last, wbf);
  k_bin<<<NBINB, 256, 0, stream>>>(src, dst, bucket_cursor, binned);
  k_bucket_scan<<<1, 256, 0, stream>>>(bucket_cursor, bucket_base);
  k_build<<<NBUCK, 256, 0, stream>>>(bucket_cursor, bucket_base, binned, row_ptr, srcs);

  k_transform0<<<(NNODES + 63) / 64, 256, 0, stream>>>(x, wbf, b0_lin, b0_self, bias0, zA, s);

  const int FGRID = NNODES / 16;  // 3125
  for (int k = 0; k < NLAYERS; ++k) {
    ushort* zin = (k % 2 == 0) ? zA : zB;
    ushort* zout = (k % 2 == 0) ? zB : zA;
    int wl_ofs = 32768 + k * 16384;  // w_lin[k]/w_self[k] (producing layer k+1), k<=4
    if (k == 0) {
      k_fused<1, 1><<<FGRID, 256, 0, stream>>>(row_ptr, srcs, zin, s, wbf, wl_ofs, k,
                                               b_lin, b_self, bias, b_last, out, zout);
    } else if (k < NLAYERS - 1) {
      k_fused<1, 0><<<FGRID, 256, 0, stream>>>(row_ptr, srcs, zin, s, wbf, wl_ofs, k,
                                               b_lin + (size_t)k * 64, b_self + (size_t)k * 64,
                                               bias + (size_t)k * 64, nullptr, out, zout);
    } else {
      k_fused<0, 0><<<FGRID, 256, 0, stream>>>(row_ptr, srcs, zin, s, wbf, 0, k,
                                               nullptr, nullptr, nullptr, nullptr, out, zout);
    }
  }
}